// Round 9
// baseline (309.009 us; speedup 1.0000x reference)
//
#include <hip/hip_runtime.h>

#define LL 4
#define BB 32
#define SS 512
#define FF 768
#define NW 257        // W_MAX + 1
#define F4 192        // FF / 4

typedef float f4v __attribute__((ext_vector_type(4)));   // clang vector: nontemporal-ok

// ---- main: layer-mix + run-compressed segment-MEAN + sentence partials ----
// grid: BB * 8 * 3 blocks of 256 threads
// block -> (b, sg in 0..7 [64 s each], fc in 0..2 [64 float4 each])
// thread t: lane = t&63 -> f4 = fc*64+lane ; swave = t>>6 -> s in [s0, s0+16)
//
// Word spans are contiguous (sorted ids). A run fully inside a thread's 16-s
// window is the word's COMPLETE span -> store mean (sum/len) directly, one
// coalesced 16B store, no later fixup. Runs shared across a 16-boundary
// (wid equal across the edge) atomicAdd their partial sums; k_fix divides
// exactly those words by the histogram count.
__global__ __launch_bounds__(256, 3)
void k_main(const float* __restrict__ hs, const float* __restrict__ lw,
            const float* __restrict__ gm, const int* __restrict__ wid,
            float* __restrict__ out, float* __restrict__ partials) {
    int bid = blockIdx.x;
    int fc = bid % 3;
    int sg = (bid / 3) & 7;
    int b  = bid / 24;
    int t = threadIdx.x;
    int lane = t & 63;
    int swave = t >> 6;
    int f4 = fc * 64 + lane;
    int s0 = sg * 64 + swave * 16;

    // softmax(layer_weights) * gamma  (tiny, all-lane broadcast loads)
    float w0 = lw[0], w1 = lw[1], w2 = lw[2], w3 = lw[3];
    float mx = fmaxf(fmaxf(w0, w1), fmaxf(w2, w3));
    float e0 = __expf(w0 - mx), e1 = __expf(w1 - mx);
    float e2 = __expf(w2 - mx), e3 = __expf(w3 - mx);
    float g = gm[0] / (e0 + e1 + e2 + e3);
    float c0 = e0 * g, c1 = e1 * g, c2 = e2 * g, c3 = e3 * g;

    const f4v* h4 = (const f4v*)hs;
    const int ls = BB * SS * F4;                  // layer stride in 16B units
    int base = (b * SS + s0) * F4 + f4;
    const int* wrow = wid + b * SS + s0;

    int prev = wrow[0];
    // shared-across-boundary flags (wave-uniform)
    bool sharedL = (s0 > 0) && (wrow[-1] == prev);
    bool sharedR = (s0 + 16 < SS) && (wrow[16] == wrow[15]);

    f4v sent = {0.f, 0.f, 0.f, 0.f};
    f4v run  = {0.f, 0.f, 0.f, 0.f};
    int len = 0;
    bool first = true;

    #pragma unroll
    for (int k = 0; k < 16; k++) {
        int w = wrow[k];                          // wave-uniform (all lanes same s)
        int idx = base + k * F4;
        f4v a  = __builtin_nontemporal_load(&h4[idx]);
        f4v bv = __builtin_nontemporal_load(&h4[idx + ls]);
        f4v cv = __builtin_nontemporal_load(&h4[idx + 2 * ls]);
        f4v dv = __builtin_nontemporal_load(&h4[idx + 3 * ls]);
        f4v v = c0 * a + c1 * bv + c2 * cv + c3 * dv;
        sent += v;
        if (w != prev) {                          // wave-uniform branch
            float* p = out + (prev + b * NW) * FF + f4 * 4;
            if (first && sharedL) {               // partial span: atomic sum
                atomicAdd(p + 0, run.x); atomicAdd(p + 1, run.y);
                atomicAdd(p + 2, run.z); atomicAdd(p + 3, run.w);
            } else {                              // complete span: store mean
                *(f4v*)p = run * (1.0f / (float)len);
            }
            first = false;
            run = v; len = 1; prev = w;
        } else {
            run += v; len++;
        }
    }
    {   // final run
        float* p = out + (prev + b * NW) * FF + f4 * 4;
        if ((first && sharedL) || sharedR) {
            atomicAdd(p + 0, run.x); atomicAdd(p + 1, run.y);
            atomicAdd(p + 2, run.z); atomicAdd(p + 3, run.w);
        } else {
            *(f4v*)p = run * (1.0f / (float)len);
        }
    }

    // sentence partial: reduce the 4 s-waves, one non-atomic store per (b,sg,f4)
    __shared__ f4v sm[256];
    sm[t] = sent;
    __syncthreads();
    if (t < 64) {
        f4v tot = sm[t] + sm[t + 64] + sm[t + 128] + sm[t + 192];
        ((f4v*)partials)[(b * 8 + sg) * F4 + f4] = tot;   // f4 == fc*64 + t
    }
}

// ---- fixup: divide boundary-shared words; sentence mean into slot 0 ----
// grid: BB blocks of 512 threads
__global__ void k_fix(const int* __restrict__ wid,
                      const float* __restrict__ partials,
                      float* __restrict__ out) {
    __shared__ int lc[NW];
    __shared__ int flag[NW];
    int b = blockIdx.x;
    int t = threadIdx.x;
    for (int i = t; i < NW; i += 512) { lc[i] = 0; flag[i] = 0; }
    __syncthreads();
    int w = wid[b * SS + t];
    atomicAdd(&lc[w], 1);
    if (t > 0 && (t & 15) == 0) {                 // 16-boundaries s=16..496
        if (wid[b * SS + t - 1] == w) flag[w] = 1;
    }
    __syncthreads();
    // divide flagged (boundary-shared) words once by total count
    for (int w2 = 1; w2 < NW; ++w2) {
        if (flag[w2]) {                            // wave-uniform LDS broadcast
            float inv = 1.0f / (float)(lc[w2] > 1 ? lc[w2] : 1);
            float* p = out + ((size_t)b * NW + w2) * FF;
            for (int f = t; f < FF; f += 512) p[f] *= inv;
        }
    }
    // sentence mean into slot 0
    const float* pp = partials + (size_t)b * 8 * FF;
    for (int f = t; f < FF; f += 512) {
        float s = 0.f;
        #pragma unroll
        for (int gg = 0; gg < 8; gg++) s += pp[gg * FF + f];
        out[(size_t)b * NW * FF + f] = s * (1.0f / (float)SS);
    }
}

extern "C" void kernel_launch(void* const* d_in, const int* in_sizes, int n_in,
                              void* d_out, int out_size, void* d_ws, size_t ws_size,
                              hipStream_t stream) {
    const float* hs  = (const float*)d_in[0];   // (L,B,S,F) f32
    const float* lw  = (const float*)d_in[1];   // (L,)
    const float* gm  = (const float*)d_in[2];   // (1,)
    const int*   wid = (const int*)d_in[3];     // (B,S) int32, sorted per row
    float* out = (float*)d_out;                 // (B, 257, F) f32

    float* partials = (float*)d_ws;             // BB*8*FF floats = 786 KB

    (void)hipMemsetAsync(d_out, 0, (size_t)out_size * sizeof(float), stream);
    k_main<<<BB * 24, 256, 0, stream>>>(hs, lw, gm, wid, out, partials);
    k_fix<<<BB, 512, 0, stream>>>(wid, partials, out);
}